// Round 1
// baseline (397.507 us; speedup 1.0000x reference)
//
#include <hip/hip_runtime.h>
#include <hip/hip_bf16.h>
#include <stdint.h>
#include <stddef.h>

typedef __bf16 bf16;
typedef __attribute__((ext_vector_type(8))) __bf16 bf16x8;
typedef __attribute__((ext_vector_type(4))) __bf16 bf16x4;
typedef __attribute__((ext_vector_type(4))) float f32x4;
typedef __attribute__((ext_vector_type(8))) unsigned short ushort8;

#define DM 2048      // model dim
#define NH 16        // heads
#define HDD 128      // head dim
#define BB 2         // batch
#define TT 2048      // seq len
#define MM (BB*TT)   // 4096 rows
#define NQKV (3*DM)  // 6144

#define L2E 1.4426950408889634f
#define ATT_SCALE 0.08838834764831845f   // 1/sqrt(128)
#define NEG_INF (-__builtin_inff())

static_assert(sizeof(bf16x8) == 16, "bf16x8 must be 16B");

// ---------------------------------------------------------------- helpers
static __device__ __forceinline__ void gload_lds16(const void* g, void* l) {
  // async global->LDS, 16B per lane; LDS dest = wave-uniform base + lane*16
  __builtin_amdgcn_global_load_lds(
      (__attribute__((address_space(1))) void*)g,
      (__attribute__((address_space(3))) void*)l, 16, 0, 0);
}

// ---------------------------------------------------------------- pre-pass
__global__ __launch_bounds__(256) void rope_table_k(float* __restrict__ cT,
                                                    float* __restrict__ sT) {
  int id = blockIdx.x * 256 + threadIdx.x;          // < 2048*64
  int t = id >> 6, i = id & 63;
  float freq = powf(10000.0f, -(float)i * (1.0f / 64.0f));
  float theta = (float)t * freq;
  float s, c;
  __sincosf(theta, &s, &c);
  cT[id] = c;
  sT[id] = s;
}

__global__ __launch_bounds__(256) void convert_x_k(const float* __restrict__ x,
                                                   bf16* __restrict__ xb) {
  size_t id = (size_t)blockIdx.x * 256 + threadIdx.x;   // 1,048,576 threads
  size_t o = id * 8;
  float4 a = *(const float4*)(x + o);
  float4 b = *(const float4*)(x + o + 4);
  bf16x8 r;
  r[0] = (bf16)a.x; r[1] = (bf16)a.y; r[2] = (bf16)a.z; r[3] = (bf16)a.w;
  r[4] = (bf16)b.x; r[5] = (bf16)b.y; r[6] = (bf16)b.z; r[7] = (bf16)b.w;
  *(bf16x8*)(xb + o) = r;
}

// W (K x N) f32 -> Wt (N x K) bf16, 64x64 tiles
__global__ __launch_bounds__(256) void transpose_w_k(const float* __restrict__ W,
                                                     bf16* __restrict__ Wt,
                                                     int K, int N) {
  __shared__ float tile[64][65];
  int n0 = blockIdx.x * 64, k0 = blockIdx.y * 64;
  int t = threadIdx.x;
#pragma unroll
  for (int i = 0; i < 16; ++i) {
    int idx = t + i * 256;
    int r = idx >> 6, c = idx & 63;
    tile[r][c] = W[(size_t)(k0 + r) * N + n0 + c];
  }
  __syncthreads();
#pragma unroll
  for (int i = 0; i < 16; ++i) {
    int idx = t + i * 256;
    int r = idx >> 6, c = idx & 63;
    Wt[(size_t)(n0 + r) * K + k0 + c] = (bf16)tile[c][r];
  }
}

// in-place RoPE on (b,h,t,hd) bf16 buffer; half-split style
__global__ __launch_bounds__(256) void rope_apply_k(bf16* __restrict__ buf,
                                                    const float* __restrict__ cT,
                                                    const float* __restrict__ sT) {
  int id = blockIdx.x * 256 + threadIdx.x;   // < 32*2048*16
  int i4 = id & 15;
  int t = (id >> 4) & 2047;
  int bh = id >> 15;
  int idx0 = i4 * 4;
  size_t base = ((size_t)bh * TT + t) * HDD;
  bf16x4 x1 = *(const bf16x4*)(buf + base + idx0);
  bf16x4 x2 = *(const bf16x4*)(buf + base + 64 + idx0);
  float4 ct = *(const float4*)(cT + t * 64 + idx0);
  float4 st = *(const float4*)(sT + t * 64 + idx0);
  bf16x4 o1, o2;
  float c0, s0, a, b2;
#pragma unroll
  for (int j = 0; j < 4; ++j) {
    c0 = (j == 0) ? ct.x : (j == 1) ? ct.y : (j == 2) ? ct.z : ct.w;
    s0 = (j == 0) ? st.x : (j == 1) ? st.y : (j == 2) ? st.z : st.w;
    a = (float)x1[j];
    b2 = (float)x2[j];
    o1[j] = (bf16)(a * c0 - b2 * s0);
    o2[j] = (bf16)(a * s0 + b2 * c0);
  }
  *(bf16x4*)(buf + base + idx0) = o1;
  *(bf16x4*)(buf + base + 64 + idx0) = o2;
}

// ---------------------------------------------------------------- GEMM
// C(M,N) = A(M,K) * Bt(N,K)^T + bias.  128x128 tile, BK=64, 4 waves 2x2.
// EPI 0: cast bf16, scatter to q/k/v in (b,head,t,hd); EPI 1: f32 out row-major.
template <int EPI>
__global__ __launch_bounds__(256, 2) void gemm_bt_k(
    const bf16* __restrict__ A, const bf16* __restrict__ Bt,
    const float* __restrict__ bias,
    bf16* __restrict__ q_out, bf16* __restrict__ k_out, bf16* __restrict__ v_out,
    float* __restrict__ c_out, int M, int N, int K) {
  __shared__ __align__(16) bf16 Asm[128 * 64];
  __shared__ __align__(16) bf16 Bsm[128 * 64];
  const int tid = threadIdx.x;
  const int w = tid >> 6, l = tid & 63;
  const int lane16 = l & 15, lgrp = l >> 4;
  const int wm = w >> 1, wn = w & 1;
  const int bm = blockIdx.x, bn = blockIdx.y;
  const int l8r = l >> 3, l8c = l & 7;

  f32x4 acc[4][4] = {};

  for (int k0 = 0; k0 < K; k0 += 64) {
    __syncthreads();
#pragma unroll
    for (int i = 0; i < 4; ++i) {
      int slot = w * 4 + i;          // 0..15, 8 rows each
      int row = slot * 8 + l8r;
      gload_lds16(A + (size_t)(bm * 128 + row) * K + k0 + l8c * 8,
                  &Asm[slot * 512]);
      gload_lds16(Bt + (size_t)(bn * 128 + row) * K + k0 + l8c * 8,
                  &Bsm[slot * 512]);
    }
    __syncthreads();
#pragma unroll
    for (int kk = 0; kk < 2; ++kk) {
      bf16x8 af[4], bfr[4];
#pragma unroll
      for (int mf = 0; mf < 4; ++mf) {
        int row = wm * 64 + mf * 16 + lane16;
        af[mf] = *(const bf16x8*)&Asm[row * 64 + kk * 32 + lgrp * 8];
      }
#pragma unroll
      for (int nf = 0; nf < 4; ++nf) {
        int col = wn * 64 + nf * 16 + lane16;
        bfr[nf] = *(const bf16x8*)&Bsm[col * 64 + kk * 32 + lgrp * 8];
      }
#pragma unroll
      for (int mf = 0; mf < 4; ++mf)
#pragma unroll
        for (int nf = 0; nf < 4; ++nf)
          acc[mf][nf] = __builtin_amdgcn_mfma_f32_16x16x32_bf16(
              af[mf], bfr[nf], acc[mf][nf], 0, 0, 0);
    }
  }

  if (EPI == 0) {
    const int which = bn >> 4;   // 16 N-blocks (of 128) per matrix
    const int head = bn & 15;
    bf16* outb = (which == 0) ? q_out : (which == 1 ? k_out : v_out);
#pragma unroll
    for (int nf = 0; nf < 4; ++nf) {
      int hd = wn * 64 + nf * 16 + lane16;          // 0..127 within head
      float bv = bias[bn * 128 + hd];
#pragma unroll
      for (int mf = 0; mf < 4; ++mf)
#pragma unroll
        for (int r = 0; r < 4; ++r) {
          int row = bm * 128 + wm * 64 + mf * 16 + lgrp * 4 + r;
          int b = row >> 11, t = row & 2047;
          outb[((size_t)(b * NH + head) * TT + t) * HDD + hd] =
              (bf16)(acc[mf][nf][r] + bv);
        }
    }
  } else {
#pragma unroll
    for (int nf = 0; nf < 4; ++nf) {
      int colg = bn * 128 + wn * 64 + nf * 16 + lane16;
      float bv = bias[colg];
#pragma unroll
      for (int mf = 0; mf < 4; ++mf)
#pragma unroll
        for (int r = 0; r < 4; ++r) {
          int row = bm * 128 + wm * 64 + mf * 16 + lgrp * 4 + r;
          c_out[(size_t)row * N + colg] = acc[mf][nf][r] + bv;
        }
    }
  }
}

// ---------------------------------------------------------------- attention
// grid: (T/128, B*H). 4 waves, wave w owns rows {q0+w*16..+15, q0+64+w*16..+15}.
__global__ __launch_bounds__(256, 2) void attn_k(
    const bf16* __restrict__ Q, const bf16* __restrict__ Kt,
    const bf16* __restrict__ V, bf16* __restrict__ Y) {
  __shared__ __align__(16) bf16 Ksm[64 * 128];   // [key][hd], row-swizzled
  __shared__ __align__(16) bf16 Vsm[128 * 64];   // [hd][key], row-swizzled
  __shared__ __align__(16) bf16 Psm[4][32 * 64]; // per-wave P, row-swizzled
  const int tid = threadIdx.x, w = tid >> 6, l = tid & 63;
  const int lane16 = l & 15, lgrp = l >> 4;
  const int q0 = blockIdx.x * 128;
  const int bh = blockIdx.y;
  const int b = bh >> 4, h = bh & 15;
  const size_t base = (size_t)bh * TT * HDD;

  // Q fragments (registers)
  bf16x8 qa[2][4];
#pragma unroll
  for (int mf = 0; mf < 2; ++mf) {
    int row = q0 + mf * 64 + w * 16 + lane16;
#pragma unroll
    for (int kk = 0; kk < 4; ++kk)
      qa[mf][kk] = *(const bf16x8*)(Q + base + (size_t)row * HDD + kk * 32 + lgrp * 8);
  }

  f32x4 o[2][8] = {};
  float m_r[2][4], l_r[2][4];
#pragma unroll
  for (int mf = 0; mf < 2; ++mf)
#pragma unroll
    for (int r = 0; r < 4; ++r) { m_r[mf][r] = NEG_INF; l_r[mf][r] = 0.f; }

  const int nt = (q0 + 128) / 64;
  for (int kt = 0; kt < nt; ++kt) {
    const int k0 = kt * 64;
    __syncthreads();
    // ---- stage K [key][hd], byte ^= (key&7)<<4
#pragma unroll
    for (int i = 0; i < 4; ++i) {
      int flat8 = tid * 4 + i;
      int key = flat8 >> 4, hb = flat8 & 15;
      uint4 d = *(const uint4*)(Kt + base + (size_t)(k0 + key) * HDD + hb * 8);
      int byte = (hb * 16) ^ ((key & 7) << 4);
      *(uint4*)((char*)Ksm + key * 256 + byte) = d;
    }
    // ---- stage V transposed: Vsm[hd][key], byte ^= ((hd&7)^((hd>>3)&7))<<4
    {
      int g = tid >> 4, h8 = tid & 15;
      int hd0 = h8 * 8;
      ushort8 vv[4];
#pragma unroll
      for (int kq = 0; kq < 4; ++kq) {
        uint4 d = *(const uint4*)(V + base + (size_t)(k0 + g * 4 + kq) * HDD + hd0);
        vv[kq] = __builtin_bit_cast(ushort8, d);
      }
#pragma unroll
      for (int j = 0; j < 8; ++j) {
        int hd = hd0 + j;
        int swz = ((hd & 7) ^ ((hd >> 3) & 7)) << 4;
        uint2 val;
        val.x = (unsigned)vv[0][j] | ((unsigned)vv[1][j] << 16);
        val.y = (unsigned)vv[2][j] | ((unsigned)vv[3][j] << 16);
        *(uint2*)((char*)Vsm + hd * 128 + ((g * 8) ^ swz)) = val;
      }
    }
    __syncthreads();

    bool act[2];
    act[0] = (k0 <= q0 + w * 16 + 15);
    act[1] = true;   // k0 <= q0+64 always
    f32x4 s[2][4] = {};

    // ---- S = Q K^T
#pragma unroll
    for (int kk = 0; kk < 4; ++kk) {
      bf16x8 kf[4];
#pragma unroll
      for (int nf = 0; nf < 4; ++nf) {
        int key = nf * 16 + lane16;
        int byte = ((kk * 32 + lgrp * 8) * 2) ^ ((key & 7) << 4);
        kf[nf] = *(const bf16x8*)((char*)Ksm + key * 256 + byte);
      }
#pragma unroll
      for (int mf = 0; mf < 2; ++mf)
        if (act[mf])
#pragma unroll
          for (int nf = 0; nf < 4; ++nf)
            s[mf][nf] = __builtin_amdgcn_mfma_f32_16x16x32_bf16(
                qa[mf][kk], kf[nf], s[mf][nf], 0, 0, 0);
    }

    // ---- scale + causal mask + online softmax + P write
#pragma unroll
    for (int mf = 0; mf < 2; ++mf) {
      if (!act[mf]) continue;
      const int rowbase = q0 + mf * 64 + w * 16 + lgrp * 4;
      const bool needmask = (k0 + 63 > q0 + mf * 64 + w * 16);
#pragma unroll
      for (int nf = 0; nf < 4; ++nf) {
        int col = k0 + nf * 16 + lane16;
#pragma unroll
        for (int r = 0; r < 4; ++r) {
          float sv = s[mf][nf][r] * ATT_SCALE;
          if (needmask && col > rowbase + r) sv = -3.0e38f;
          s[mf][nf][r] = sv;
        }
      }
#pragma unroll
      for (int r = 0; r < 4; ++r) {
        float tm = fmaxf(fmaxf(s[mf][0][r], s[mf][1][r]),
                         fmaxf(s[mf][2][r], s[mf][3][r]));
        tm = fmaxf(tm, __shfl_xor(tm, 1));
        tm = fmaxf(tm, __shfl_xor(tm, 2));
        tm = fmaxf(tm, __shfl_xor(tm, 4));
        tm = fmaxf(tm, __shfl_xor(tm, 8));
        float mo = m_r[mf][r];
        float mn, alpha;
        if (tm > -1e37f) {           // row has live cols this tile
          mn = fmaxf(mo, tm);
          alpha = exp2f((mo - mn) * L2E);
        } else {                     // fully-masked row: contribute nothing
          mn = mo;
          alpha = 1.0f;
        }
        m_r[mf][r] = mn;
        float rs = 0.f;
#pragma unroll
        for (int nf = 0; nf < 4; ++nf) {
          float p = exp2f((s[mf][nf][r] - mn) * L2E);
          s[mf][nf][r] = p;
          rs += p;
        }
        rs += __shfl_xor(rs, 1);
        rs += __shfl_xor(rs, 2);
        rs += __shfl_xor(rs, 4);
        rs += __shfl_xor(rs, 8);
        l_r[mf][r] = l_r[mf][r] * alpha + rs;
#pragma unroll
        for (int nf = 0; nf < 8; ++nf) o[mf][nf][r] *= alpha;
      }
      // write P (D-layout -> LDS, swizzled)
#pragma unroll
      for (int nf = 0; nf < 4; ++nf)
#pragma unroll
        for (int r = 0; r < 4; ++r) {
          int rl = mf * 16 + lgrp * 4 + r;
          int byte = ((nf * 16 + lane16) * 2) ^ ((rl & 7) << 4);
          *(bf16*)((char*)&Psm[w][0] + rl * 128 + byte) = (bf16)s[mf][nf][r];
        }
    }

    // ---- O += P V
    bf16x8 pa[2][2];
#pragma unroll
    for (int mf = 0; mf < 2; ++mf)
      if (act[mf])
#pragma unroll
        for (int kf = 0; kf < 2; ++kf) {
          int rl = mf * 16 + lane16;
          int byte = ((kf * 32 + lgrp * 8) * 2) ^ ((rl & 7) << 4);
          pa[mf][kf] = *(const bf16x8*)((char*)&Psm[w][0] + rl * 128 + byte);
        }
#pragma unroll
    for (int nf = 0; nf < 8; ++nf) {
#pragma unroll
      for (int kf = 0; kf < 2; ++kf) {
        int hd = nf * 16 + lane16;
        int byte = ((kf * 32 + lgrp * 8) * 2) ^ (((hd & 7) ^ ((hd >> 3) & 7)) << 4);
        bf16x8 vf = *(const bf16x8*)((char*)Vsm + hd * 128 + byte);
#pragma unroll
        for (int mf = 0; mf < 2; ++mf)
          if (act[mf])
            o[mf][nf] = __builtin_amdgcn_mfma_f32_16x16x32_bf16(
                pa[mf][kf], vf, o[mf][nf], 0, 0, 0);
      }
    }
  }

  // ---- finalize: O / l -> Y (b,t,D) bf16
#pragma unroll
  for (int mf = 0; mf < 2; ++mf)
#pragma unroll
    for (int r = 0; r < 4; ++r) {
      float inv = 1.0f / l_r[mf][r];
      int row = q0 + mf * 64 + w * 16 + lgrp * 4 + r;
#pragma unroll
      for (int nf = 0; nf < 8; ++nf) {
        int hd = nf * 16 + lane16;
        Y[(size_t)(b * TT + row) * DM + h * HDD + hd] = (bf16)(o[mf][nf][r] * inv);
      }
    }
}

// ---------------------------------------------------------------- launch
extern "C" void kernel_launch(void* const* d_in, const int* in_sizes, int n_in,
                              void* d_out, int out_size, void* d_ws, size_t ws_size,
                              hipStream_t stream) {
  const float* x = (const float*)d_in[0];
  // d_in[1]: mask (tril) — causal, handled analytically
  const float* Wqkv = (const float*)d_in[2];
  const float* bqkv = (const float*)d_in[3];
  const float* Wproj = (const float*)d_in[4];
  const float* bproj = (const float*)d_in[5];
  float* out = (float*)d_out;

  char* ws = (char*)d_ws;
  bf16* xb = (bf16*)ws;                 ws += (size_t)MM * DM * 2;        // 16.8 MB (also yb later)
  bf16* Wqkvt = (bf16*)ws;              ws += (size_t)NQKV * DM * 2;      // 25.2 MB
  bf16* Wprojt = (bf16*)ws;             ws += (size_t)DM * DM * 2;        // 8.4 MB
  bf16* kb = (bf16*)ws;                 ws += (size_t)MM * DM * 2;        // 16.8 MB
  bf16* vb = (bf16*)ws;                 ws += (size_t)MM * DM * 2;        // 16.8 MB
  float* cosT = (float*)ws;             ws += (size_t)TT * 64 * 4;        // 0.5 MB
  float* sinT = (float*)ws;             ws += (size_t)TT * 64 * 4;        // 0.5 MB
  bf16* qb = (bf16*)d_out;              // q lives in d_out (overwritten by proj at the end)
  bf16* yb = xb;                        // xb dead after QKV GEMM

  rope_table_k<<<dim3(512), dim3(256), 0, stream>>>(cosT, sinT);
  convert_x_k<<<dim3(4096), dim3(256), 0, stream>>>(x, xb);
  transpose_w_k<<<dim3(96, 32), dim3(256), 0, stream>>>(Wqkv, Wqkvt, DM, NQKV);
  transpose_w_k<<<dim3(32, 32), dim3(256), 0, stream>>>(Wproj, Wprojt, DM, DM);

  gemm_bt_k<0><<<dim3(32, 48), dim3(256), 0, stream>>>(
      xb, Wqkvt, bqkv, qb, kb, vb, nullptr, MM, NQKV, DM);

  rope_apply_k<<<dim3(4096), dim3(256), 0, stream>>>(qb, cosT, sinT);
  rope_apply_k<<<dim3(4096), dim3(256), 0, stream>>>(kb, cosT, sinT);

  attn_k<<<dim3(16, 32), dim3(256), 0, stream>>>(qb, kb, vb, yb);

  gemm_bt_k<1><<<dim3(32, 16), dim3(256), 0, stream>>>(
      yb, Wprojt, bproj, nullptr, nullptr, nullptr, out, MM, DM, DM);
}